// Round 5
// baseline (842.375 us; speedup 1.0000x reference)
//
#include <hip/hip_runtime.h>
#include <cmath>

#define BB 4
#define NN 4096
#define CC 1024
#define HH 8
#define DD 128
#define MM (BB*NN)   // 16384
#define NP (NN+2)    // padded rows per batch

typedef __attribute__((ext_vector_type(8))) short bf16x8;
typedef __attribute__((ext_vector_type(4))) float f32x4;

static __device__ __forceinline__ unsigned short f2bf(float f) {
    unsigned int u = __float_as_uint(f);
    unsigned int r = (u + 0x7FFF + ((u >> 16) & 1)) >> 16;
    return (unsigned short)r;
}
static __device__ __forceinline__ float bf2f(short s) {
    return __uint_as_float(((unsigned int)(unsigned short)s) << 16);
}
static __device__ __forceinline__ float4 bf4(ushort4 u) {
    float4 f;
    f.x = __uint_as_float((unsigned int)u.x << 16);
    f.y = __uint_as_float((unsigned int)u.y << 16);
    f.z = __uint_as_float((unsigned int)u.z << 16);
    f.w = __uint_as_float((unsigned int)u.w << 16);
    return f;
}

static __device__ __forceinline__ void load_lds16(const void* g, void* l) {
    __builtin_amdgcn_global_load_lds(
        (const __attribute__((address_space(1))) unsigned int*)g,
        (__attribute__((address_space(3))) unsigned int*)l, 16, 0, 0);
}

// ---------------------------------------------------------------------------
// P1: xpad[b][p][c] (bf16), p in [0,NP): rows 0 and NP-1 zero, p = x[b][p-1]
// ---------------------------------------------------------------------------
__global__ __launch_bounds__(256) void padx_kernel(
    const float* __restrict__ x, unsigned short* __restrict__ xpad)
{
    const int r = blockIdx.x;
    const int b = r / NP, p = r % NP;
    const int c = threadIdx.x * 4;
    ushort4 v = {0, 0, 0, 0};
    if (p >= 1 && p <= NN) {
        const float4 f = *(const float4*)&x[(size_t)(b * NN + p - 1) * CC + c];
        v.x = f2bf(f.x); v.y = f2bf(f.y); v.z = f2bf(f.z); v.w = f2bf(f.w);
    }
    *(ushort4*)&xpad[(size_t)r * CC + c] = v;
}

// ---------------------------------------------------------------------------
// P2: dst[c][r] = bf16(src[r][c])
// ---------------------------------------------------------------------------
__global__ __launch_bounds__(256) void transpose_bf16_kernel(
    const float* __restrict__ src, unsigned short* __restrict__ dst,
    int R, int Cc)
{
    __shared__ float t[32][33];
    const int r0 = blockIdx.y * 32, c0 = blockIdx.x * 32;
    const int tx = threadIdx.x & 31, ty = threadIdx.x >> 5;
    #pragma unroll
    for (int i = 0; i < 4; ++i) {
        int r = ty + i * 8;
        t[r][tx] = src[(size_t)(r0 + r) * Cc + c0 + tx];
    }
    __syncthreads();
    #pragma unroll
    for (int i = 0; i < 4; ++i) {
        int r = ty + i * 8;
        dst[(size_t)(c0 + r) * R + r0 + tx] = f2bf(t[tx][r]);
    }
}

// ---------------------------------------------------------------------------
// K1: qk = x @ qk_w + qk_b ; elu+1 ; q,k stored bf16; k column sums -> ksum
// ---------------------------------------------------------------------------
__global__ __launch_bounds__(256) void gemm_qk_mfma(
    const unsigned short* __restrict__ xpad, const unsigned short* __restrict__ wT,
    const float* __restrict__ bias, unsigned short* __restrict__ qbuf,
    unsigned short* __restrict__ kbuf, float* __restrict__ ksum)
{
    __shared__ __align__(16) unsigned short As[4096];  // 128 x 32 bf16
    __shared__ __align__(16) unsigned short Bs[4096];
    const int m0 = blockIdx.x * 128;
    const int n0 = blockIdx.y * 128;
    const int tid = threadIdx.x;
    const int lane = tid & 63;
    const int wv = tid >> 6;
    const int rowoff = m0 + 1 + 2 * (m0 >> 12);

    f32x4 acc[4][4] = {};
    for (int k0 = 0; k0 < CC; k0 += 32) {
        #pragma unroll
        for (int p = 0; p < 2; ++p) {
            const int c = p * 256 + wv * 64 + lane;
            const int row = ((c >> 6) << 4) | (c & 15);
            const int quad = (c >> 4) & 3;
            load_lds16(&xpad[(size_t)(rowoff + row) * CC + k0 + quad * 8],
                       &As[(size_t)(p * 256 + wv * 64) * 8]);
            load_lds16(&wT[(size_t)(n0 + row) * CC + k0 + quad * 8],
                       &Bs[(size_t)(p * 256 + wv * 64) * 8]);
        }
        __syncthreads();
        bf16x8 a[4], b[4];
        #pragma unroll
        for (int mt = 0; mt < 4; ++mt)
            a[mt] = *(const bf16x8*)&As[(((wv & 1) * 4 + mt) * 64 + lane) * 8];
        #pragma unroll
        for (int nt = 0; nt < 4; ++nt)
            b[nt] = *(const bf16x8*)&Bs[(((wv >> 1) * 4 + nt) * 64 + lane) * 8];
        #pragma unroll
        for (int mt = 0; mt < 4; ++mt)
            #pragma unroll
            for (int nt = 0; nt < 4; ++nt)
                acc[mt][nt] = __builtin_amdgcn_mfma_f32_16x16x32_bf16(
                    a[mt], b[nt], acc[mt][nt], 0, 0, 0);
        __syncthreads();
    }
    const int wm = (wv & 1) * 64, wn = (wv >> 1) * 64;
    const int col = lane & 15, rbase = (lane >> 4) * 4;
    const bool khalf = (n0 >= CC);
    const int b = m0 >> 12;
    #pragma unroll
    for (int nt = 0; nt < 4; ++nt) {
        const int n = n0 + wn + nt * 16 + col;
        const float bn = bias[n];
        float csum = 0.0f;
        #pragma unroll
        for (int mt = 0; mt < 4; ++mt)
            #pragma unroll
            for (int r = 0; r < 4; ++r) {
                const int m = m0 + wm + mt * 16 + rbase + r;
                float v = acc[mt][nt][r] + bn;
                v = (v > 0.0f) ? (v + 1.0f) : expf(v);   // elu(v)+1
                csum += v;
                if (!khalf) qbuf[(size_t)m * CC + n] = f2bf(v);
                else        kbuf[(size_t)m * CC + (n - CC)] = f2bf(v);
            }
        if (khalf) atomicAdd(&ksum[b * CC + (n - CC)], csum);
    }
}

// ---------------------------------------------------------------------------
// K3: thread = (row, head). z[m,hp] = 1/(dot(q_head hp, ksum_head hp)/N+1e-6)
// shared via LDS; qbuf <- z-scaled RoPE'd q (zq) in place; kr -> krP bf16.
// pr-half of orig head h lands in rope-head h>>1 (scale z[h>>1]);
// pi-half lands in rope-head 4+(h>>1) (scale z[4+(h>>1)]).
// ---------------------------------------------------------------------------
__global__ __launch_bounds__(256) void rope_z_kernel(
    unsigned short* __restrict__ qbuf, const unsigned short* __restrict__ kbuf,
    const float* __restrict__ ksum, unsigned short* __restrict__ krP)
{
    __shared__ float zsh[32][8];
    const int tid = threadIdx.x;
    const int row = tid >> 3;            // 0..31
    const int h = tid & 7;
    const int m = blockIdx.x * 32 + row;
    const int b = m >> 12;
    const int pos = m & (NN - 1);
    unsigned short* qrow = qbuf + (size_t)m * CC + h * DD;
    const unsigned short* krow = kbuf + (size_t)m * CC + h * DD;

    bf16x8 qv[16], kv8[16];
    #pragma unroll
    for (int i = 0; i < 16; ++i) {
        qv[i]  = *(const bf16x8*)&qrow[i * 8];
        kv8[i] = *(const bf16x8*)&krow[i * 8];
    }
    // z for pre-rope head h
    const float* km = ksum + b * CC + h * DD;
    float dot = 0.0f;
    #pragma unroll
    for (int i = 0; i < 16; ++i)
        #pragma unroll
        for (int jq = 0; jq < 8; ++jq)
            dot = fmaf(bf2f(qv[i][jq]), km[i * 8 + jq], dot);
    zsh[row][h] = 1.0f / (dot * (1.0f / (float)NN) + 1e-6f);
    __syncthreads();   // zsh ready AND all in-place q reads complete
    const float z1 = zsh[row][h >> 1];
    const float z2 = zsh[row][4 + (h >> 1)];

    #pragma unroll
    for (int c8 = 0; c8 < 8; ++c8) {
        bf16x8 qpr, qpi, kpr, kpi;
        #pragma unroll
        for (int u = 0; u < 8; ++u) {
            const int jj = c8 * 8 + u;
            const int j = h * 64 + jj;           // global pair index 0..511
            const float theta = __builtin_exp2f((float)j * (-13.287712379549449f / 512.0f));
            float sv, cv;
            sincosf((float)pos * theta, &sv, &cv);
            const int li = c8 * 2 + (u >> 2);
            const int le = (2 * u) & 7;
            const float q0 = bf2f(qv[li][le]),  q1 = bf2f(qv[li][le + 1]);
            const float k0 = bf2f(kv8[li][le]), k1 = bf2f(kv8[li][le + 1]);
            qpr[u] = (short)f2bf((cv * q0 - sv * q1) * z1);
            qpi[u] = (short)f2bf((cv * q1 + sv * q0) * z2);
            kpr[u] = (short)f2bf(cv * k0 - sv * k1);
            kpi[u] = (short)f2bf(cv * k1 + sv * k0);
        }
        *(bf16x8*)&qbuf[(size_t)m * CC + h * 64 + c8 * 8] = qpr;
        *(bf16x8*)&qbuf[(size_t)m * CC + 512 + h * 64 + c8 * 8] = qpi;
        unsigned short* kp1 = &krP[((size_t)(b * 8 + (h >> 1)) * NN + pos) * DD + (h & 1) * 64 + c8 * 8];
        unsigned short* kp2 = &krP[((size_t)(b * 8 + 4 + (h >> 1)) * NN + pos) * DD + (h & 1) * 64 + c8 * 8];
        *(bf16x8*)kp1 = kpr;
        *(bf16x8*)kp2 = kpi;
    }
}

// ---------------------------------------------------------------------------
// K4: kvpart[slice][bh][d][e] = sum over slice's 256 n of kr[n,d]*v[n,e]
// ---------------------------------------------------------------------------
__global__ __launch_bounds__(256) void kv_kernel(
    const unsigned short* __restrict__ krP, const unsigned short* __restrict__ xpad,
    float* __restrict__ kvpart)
{
    __shared__ float ksm[8][132];
    __shared__ float vsm[8][132];
    const int bh = blockIdx.x;                 // 0..31
    const int slice = blockIdx.y;              // 0..15
    const int b = bh >> 3, h = bh & 7;
    const int n0 = slice * 256;
    const int tid = threadIdx.x;
    const int td = (tid >> 4) * 8;
    const int te = (tid & 15) * 8;
    const unsigned short* kp = krP + ((size_t)bh * NN + n0) * DD;
    const unsigned short* vp = xpad + ((size_t)(b * NP) + 1 + n0) * CC + h * DD;
    const int sr = tid >> 5;
    const int sc = (tid & 31) * 4;
    float acc[8][8] = {};
    for (int r0 = 0; r0 < 256; r0 += 8) {
        const ushort4 kq = *(const ushort4*)&kp[(size_t)(r0 + sr) * DD + sc];
        const ushort4 vq = *(const ushort4*)&vp[(size_t)(r0 + sr) * CC + sc];
        *(float4*)&ksm[sr][sc] = bf4(kq);
        *(float4*)&vsm[sr][sc] = bf4(vq);
        __syncthreads();
        #pragma unroll
        for (int r = 0; r < 8; ++r) {
            float a[8], bv[8];
            *(float4*)&a[0]  = *(const float4*)&ksm[r][td];
            *(float4*)&a[4]  = *(const float4*)&ksm[r][td + 4];
            *(float4*)&bv[0] = *(const float4*)&vsm[r][te];
            *(float4*)&bv[4] = *(const float4*)&vsm[r][te + 4];
            #pragma unroll
            for (int i = 0; i < 8; ++i)
                #pragma unroll
                for (int j = 0; j < 8; ++j)
                    acc[i][j] = fmaf(a[i], bv[j], acc[i][j]);
        }
        __syncthreads();
    }
    float* op = kvpart + ((size_t)slice * 32 + bh) * (DD * DD);
    #pragma unroll
    for (int i = 0; i < 8; ++i)
        #pragma unroll
        for (int j = 0; j < 8; j += 4)
            *(float4*)&op[(td + i) * DD + te + j] = *(float4*)&acc[i][j];
}

// ---------------------------------------------------------------------------
// K4b: kvT[bh][e][d] = bf16( (1/64) * sum_sl kvpart[sl][bh][d][e] )
// one block per bh; coalesced reads, scattered bf16 writes (tiny kernel)
// ---------------------------------------------------------------------------
__global__ __launch_bounds__(256) void kv_reduce_T_kernel(
    const float* __restrict__ kvpart, unsigned short* __restrict__ kvT)
{
    const int bh = blockIdx.x;
    const float* base = kvpart + (size_t)bh * (DD * DD);
    unsigned short* ob = kvT + (size_t)bh * (DD * DD);
    for (int it = 0; it < 64; ++it) {
        const int idx = it * 256 + threadIdx.x;
        const int e = idx & 127, d = idx >> 7;
        float s = 0.0f;
        #pragma unroll
        for (int sl = 0; sl < 16; ++sl)
            s += base[(size_t)sl * (32 * DD * DD) + d * DD + e];
        ob[e * DD + d] = f2bf(s * (1.0f / 64.0f));
    }
}

// ---------------------------------------------------------------------------
// K6: out = conv1d(x, lepe_w) + lepe_b + attn   (fused, write-only epilogue)
// Phase 1: implicit-GEMM conv, K=3072. Phase 2: attn GEMM, K=128:
//   A = zq (z-scaled rope'd q, bf16), B = kvT[e][d]; n-tile == one head.
// ---------------------------------------------------------------------------
__global__ __launch_bounds__(256) void lepe_attn_mfma(
    const unsigned short* __restrict__ xpad, const unsigned short* __restrict__ wT,
    const unsigned short* __restrict__ zq, const unsigned short* __restrict__ kvT,
    const float* __restrict__ bias, float* __restrict__ out)
{
    __shared__ __align__(16) unsigned short As[4096];
    __shared__ __align__(16) unsigned short Bs[4096];
    const int m0 = blockIdx.x * 128;
    const int n0 = blockIdx.y * 128;
    const int h = n0 >> 7;
    const int b = m0 >> 12;
    const int tid = threadIdx.x;
    const int lane = tid & 63;
    const int wv = tid >> 6;
    const int rowoff = m0 + 1 + 2 * b;

    f32x4 acc[4][4] = {};
    // ---- phase 1: conv taps ----
    for (int k0 = 0; k0 < 3 * CC; k0 += 32) {
        const int shift = (k0 >> 10) - 1;
        const int i0 = k0 & (CC - 1);
        #pragma unroll
        for (int p = 0; p < 2; ++p) {
            const int c = p * 256 + wv * 64 + lane;
            const int row = ((c >> 6) << 4) | (c & 15);
            const int quad = (c >> 4) & 3;
            load_lds16(&xpad[(size_t)(rowoff + row + shift) * CC + i0 + quad * 8],
                       &As[(size_t)(p * 256 + wv * 64) * 8]);
            load_lds16(&wT[(size_t)(n0 + row) * (3 * CC) + k0 + quad * 8],
                       &Bs[(size_t)(p * 256 + wv * 64) * 8]);
        }
        __syncthreads();
        bf16x8 a[4], bfr[4];
        #pragma unroll
        for (int mt = 0; mt < 4; ++mt)
            a[mt] = *(const bf16x8*)&As[(((wv & 1) * 4 + mt) * 64 + lane) * 8];
        #pragma unroll
        for (int nt = 0; nt < 4; ++nt)
            bfr[nt] = *(const bf16x8*)&Bs[(((wv >> 1) * 4 + nt) * 64 + lane) * 8];
        #pragma unroll
        for (int mt = 0; mt < 4; ++mt)
            #pragma unroll
            for (int nt = 0; nt < 4; ++nt)
                acc[mt][nt] = __builtin_amdgcn_mfma_f32_16x16x32_bf16(
                    a[mt], bfr[nt], acc[mt][nt], 0, 0, 0);
        __syncthreads();
    }
    // ---- phase 2: attn (zq @ kvT^T), K=128 ----
    const unsigned short* kvp = kvT + (size_t)(b * 8 + h) * (DD * DD);
    for (int k0 = 0; k0 < DD; k0 += 32) {
        #pragma unroll
        for (int p = 0; p < 2; ++p) {
            const int c = p * 256 + wv * 64 + lane;
            const int row = ((c >> 6) << 4) | (c & 15);
            const int quad = (c >> 4) & 3;
            load_lds16(&zq[(size_t)(m0 + row) * CC + h * DD + k0 + quad * 8],
                       &As[(size_t)(p * 256 + wv * 64) * 8]);
            load_lds16(&kvp[(size_t)row * DD + k0 + quad * 8],
                       &Bs[(size_t)(p * 256 + wv * 64) * 8]);
        }
        __syncthreads();
        bf16x8 a[4], bfr[4];
        #pragma unroll
        for (int mt = 0; mt < 4; ++mt)
            a[mt] = *(const bf16x8*)&As[(((wv & 1) * 4 + mt) * 64 + lane) * 8];
        #pragma unroll
        for (int nt = 0; nt < 4; ++nt)
            bfr[nt] = *(const bf16x8*)&Bs[(((wv >> 1) * 4 + nt) * 64 + lane) * 8];
        #pragma unroll
        for (int mt = 0; mt < 4; ++mt)
            #pragma unroll
            for (int nt = 0; nt < 4; ++nt)
                acc[mt][nt] = __builtin_amdgcn_mfma_f32_16x16x32_bf16(
                    a[mt], bfr[nt], acc[mt][nt], 0, 0, 0);
        __syncthreads();
    }
    // ---- epilogue: pure store ----
    const int wm = (wv & 1) * 64, wn = (wv >> 1) * 64;
    const int col = lane & 15, rbase = (lane >> 4) * 4;
    #pragma unroll
    for (int mt = 0; mt < 4; ++mt)
        #pragma unroll
        for (int nt = 0; nt < 4; ++nt)
            #pragma unroll
            for (int r = 0; r < 4; ++r) {
                const int m = m0 + wm + mt * 16 + rbase + r;
                const int n = n0 + wn + nt * 16 + col;
                out[(size_t)m * CC + n] = acc[mt][nt][r] + bias[n];
            }
}

// ---------------------------------------------------------------------------
extern "C" void kernel_launch(void* const* d_in, const int* in_sizes, int n_in,
                              void* d_out, int out_size, void* d_ws, size_t ws_size,
                              hipStream_t stream)
{
    const float* x      = (const float*)d_in[0];
    const float* qk_w   = (const float*)d_in[1];
    const float* qk_b   = (const float*)d_in[2];
    const float* lepe_w = (const float*)d_in[3];
    const float* lepe_b = (const float*)d_in[4];
    float* out = (float*)d_out;

    // fp32 region
    float* ws     = (float*)d_ws;
    float* ksum   = ws;                                   // BB*CC
    float* kvpart = ksum + (size_t)BB * CC;               // 16*32*128*128
    // bf16 region
    unsigned short* xpad = (unsigned short*)(kvpart + (size_t)16 * 32 * DD * DD);
    unsigned short* wqT  = xpad + (size_t)BB * NP * CC;   // [2048][1024]
    unsigned short* wlT  = wqT + (size_t)2 * CC * CC;     // [1024][3072]
    unsigned short* qbuf = wlT + (size_t)CC * 3 * CC;     // M*C (q, then zq in place)
    unsigned short* kbuf = qbuf + (size_t)MM * CC;        // M*C
    unsigned short* krP  = kbuf + (size_t)MM * CC;        // [32][4096][128]
    unsigned short* kvT  = krP + (size_t)32 * NN * DD;    // [32][128][128]

    hipMemsetAsync(ksum, 0, BB * CC * sizeof(float), stream);

    padx_kernel          <<<BB * NP,                      256, 0, stream>>>(x, xpad);
    transpose_bf16_kernel<<<dim3(2 * CC / 32, CC / 32),   256, 0, stream>>>(qk_w, wqT, CC, 2 * CC);
    transpose_bf16_kernel<<<dim3(CC / 32, 3 * CC / 32),   256, 0, stream>>>(lepe_w, wlT, 3 * CC, CC);

    gemm_qk_mfma      <<<dim3(MM / 128, 2048 / 128), 256, 0, stream>>>(xpad, wqT, qk_b, qbuf, kbuf, ksum);
    rope_z_kernel     <<<MM / 32,                    256, 0, stream>>>(qbuf, kbuf, ksum, krP);
    kv_kernel         <<<dim3(32, 16),               256, 0, stream>>>(krP, xpad, kvpart);
    kv_reduce_T_kernel<<<32,                         256, 0, stream>>>(kvpart, kvT);
    lepe_attn_mfma    <<<dim3(MM / 128, CC / 128),   256, 0, stream>>>(xpad, wlT, qbuf, kvT, lepe_b, out);
}